// Round 4
// baseline (574.390 us; speedup 1.0000x reference)
//
#include <hip/hip_runtime.h>
#include <cstdint>
#include <cstddef>

// Problem constants: B=64, T=2048, M=512, P=512

typedef float  floatx4 __attribute__((ext_vector_type(4)));
typedef short  shortx8 __attribute__((ext_vector_type(8)));
typedef unsigned int uintx4 __attribute__((ext_vector_type(4)));

__device__ __forceinline__ short f2bf_rne(float f) {
  unsigned u = __float_as_uint(f);
  unsigned r = u + 0x7FFFu + ((u >> 16) & 1u);
  return (short)(r >> 16);
}

// pack two fp32 -> two bf16 (truncation) in one v_perm_b32
__device__ __forceinline__ unsigned pack_bf_trunc(float lo, float hi) {
  return __builtin_amdgcn_perm(__float_as_uint(hi), __float_as_uint(lo), 0x07060302u);
}

#define SB() __builtin_amdgcn_sched_barrier(0)
#define WAIT_VM0() asm volatile("s_waitcnt vmcnt(0)" ::: "memory")
#define WAIT_VM8() asm volatile("s_waitcnt vmcnt(8)" ::: "memory")
#define WAIT_LGKM0() asm volatile("s_waitcnt lgkmcnt(0)" ::: "memory")
#define BAR() __builtin_amdgcn_s_barrier()

// ---------------------------------------------------------------------------
// Kernel 1: prep.
//   blocks 0..127:   S[b][n] = ds@W_d + b_wd + b_ud  (fp32), 4-way ILP
//   blocks 128..383: UT[n][k] = bf16(U_d[k][n])  (plain row-major transpose)
//   blocks 384..511: zero d_out (logit accumulator)
// ---------------------------------------------------------------------------
extern "C" __global__ __launch_bounds__(256) void prep_kernel(
    const float* __restrict__ hidden, const float* __restrict__ cell,
    const float* __restrict__ W_d, const float* __restrict__ b_wd,
    const float* __restrict__ U_d, const float* __restrict__ b_ud,
    float* __restrict__ S, short* __restrict__ UT, float* __restrict__ lzero)
{
  int bx = blockIdx.x, tid = threadIdx.x;
  if (bx < 128) {
    int idx = bx * 256 + tid;          // 0..32767
    int b = idx >> 9, n = idx & 511;
    const float* h = hidden + b * 512;
    const float* c = cell   + b * 512;
    float a0 = b_wd[n] + b_ud[n], a1 = 0.f, a2 = 0.f, a3 = 0.f;
    for (int k = 0; k < 512; k += 4) {
      a0 = fmaf(h[k + 0], W_d[(k + 0) * 512 + n], a0);
      a1 = fmaf(h[k + 1], W_d[(k + 1) * 512 + n], a1);
      a2 = fmaf(h[k + 2], W_d[(k + 2) * 512 + n], a2);
      a3 = fmaf(h[k + 3], W_d[(k + 3) * 512 + n], a3);
    }
    for (int k = 0; k < 512; k += 4) {
      a0 = fmaf(c[k + 0], W_d[(k + 512) * 512 + n], a0);
      a1 = fmaf(c[k + 1], W_d[(k + 513) * 512 + n], a1);
      a2 = fmaf(c[k + 2], W_d[(k + 514) * 512 + n], a2);
      a3 = fmaf(c[k + 3], W_d[(k + 515) * 512 + n], a3);
    }
    S[idx] = (a0 + a1) + (a2 + a3);
  } else if (bx < 384) {
    int idx = (bx - 128) * 1024 + tid * 4;   // element index in UT (n*512+k)
    int n = idx >> 9, k0 = idx & 511;
    unsigned lo = (unsigned short)f2bf_rne(U_d[(size_t)(k0 + 0) * 512 + n]) |
                  ((unsigned)(unsigned short)f2bf_rne(U_d[(size_t)(k0 + 1) * 512 + n]) << 16);
    unsigned hi = (unsigned short)f2bf_rne(U_d[(size_t)(k0 + 2) * 512 + n]) |
                  ((unsigned)(unsigned short)f2bf_rne(U_d[(size_t)(k0 + 3) * 512 + n]) << 16);
    uint2 w; w.x = lo; w.y = hi;
    *(uint2*)(UT + idx) = w;
  } else {
    int idx = ((bx - 384) * 256 + tid) * 4;
    floatx4 z = {0.f, 0.f, 0.f, 0.f};
    *(floatx4*)(lzero + idx) = z;
  }
}

// ---------------------------------------------------------------------------
// Kernel 2: fused GEMM + tanh + dot(v) -> atomicAdd partial logits.
// 128x256 tile / block, 4 waves (1x4, each 128x64), BK=64, 2 phases/K-tile.
// A: fp32 global -> regs (1-iter prefetch) -> bf16 pack -> swizzled LDS.
// B: L2-resident UT -> registers DIRECTLY (no LDS), double-buffered frags.
// LDS: A only, 2 x 16 KB -> 2 blocks/CU.  Counted vmcnt, never 0 mid-loop.
// ---------------------------------------------------------------------------
struct GemmState {
  short (*As)[8192];                 // [2][128 rows][64 k] bf16 swizzled
  const float* aptr;
  const short* bfp[4];
  int afrag0, awbase;
};

template <int T>
__device__ __forceinline__ void kiter(
    GemmState& st, shortx8 (&bfr)[2][4][2], floatx4 (&areg)[8],
    floatx4 (&acc)[8][4])
{
  constexpr int CUR = T & 1;
  constexpr int NXT = CUR ^ 1;
  const short* Ab = &st.As[CUR][0];
  shortx8 af[4][2];

  // ---------------- phase A: af tr0..3; issue B(T+1) frags; 32 MFMA --------
#pragma unroll
  for (int tr = 0; tr < 4; ++tr)
#pragma unroll
    for (int s = 0; s < 2; ++s)
      af[tr][s] = *(const shortx8*)(Ab + ((st.afrag0 + tr * 1024) ^ (s * 32)));
  SB();
  if constexpr (T < 7) {
#pragma unroll
    for (int tc = 0; tc < 4; ++tc)
#pragma unroll
      for (int s = 0; s < 2; ++s)
        bfr[NXT][tc][s] = *(const shortx8*)(st.bfp[tc] + (T + 1) * 64 + s * 32);
  }
  SB();
  WAIT_LGKM0(); SB();
  __builtin_amdgcn_s_setprio(1);
#pragma unroll
  for (int tr = 0; tr < 4; ++tr)
#pragma unroll
    for (int tc = 0; tc < 4; ++tc)
#pragma unroll
      for (int s = 0; s < 2; ++s)
        acc[tr][tc] = __builtin_amdgcn_mfma_f32_16x16x32_bf16(
            af[tr][s], bfr[CUR][tc][s], acc[tr][tc], 0, 0, 0);
  __builtin_amdgcn_s_setprio(0);
  SB(); BAR(); SB();

  // ---------------- phase B: pack A(T+1)->LDS[NXT]; af tr4..7; issue A(T+2);
  //                  32 MFMA; counted drain of B(T+1) ----------------------
  if constexpr (T < 7) {
    WAIT_VM8(); SB();                // A(T+1) regs done; B(T+1) 8 in flight
    short* An = &st.As[NXT][0];
#pragma unroll
    for (int gi = 0; gi < 4; ++gi) {
      uintx4 w;
      w.x = pack_bf_trunc(areg[2 * gi].x, areg[2 * gi].y);
      w.y = pack_bf_trunc(areg[2 * gi].z, areg[2 * gi].w);
      w.z = pack_bf_trunc(areg[2 * gi + 1].x, areg[2 * gi + 1].y);
      w.w = pack_bf_trunc(areg[2 * gi + 1].z, areg[2 * gi + 1].w);
      *(uintx4*)(An + (st.awbase ^ (gi * 8))) = w;
    }
    SB();
  }
#pragma unroll
  for (int tr = 0; tr < 4; ++tr)
#pragma unroll
    for (int s = 0; s < 2; ++s)
      af[tr][s] = *(const shortx8*)(Ab + ((st.afrag0 + (tr + 4) * 1024) ^ (s * 32)));
  SB();
  if constexpr (T < 6) {
#pragma unroll
    for (int i = 0; i < 8; ++i)
      areg[i] = *(const floatx4*)(st.aptr + (T + 2) * 64 + i * 4);  // A(T+2)
  }
  SB();
  WAIT_LGKM0(); SB();
  __builtin_amdgcn_s_setprio(1);
#pragma unroll
  for (int tr = 0; tr < 4; ++tr)
#pragma unroll
    for (int tc = 0; tc < 4; ++tc)
#pragma unroll
      for (int s = 0; s < 2; ++s)
        acc[tr + 4][tc] = __builtin_amdgcn_mfma_f32_16x16x32_bf16(
            af[tr][s], bfr[CUR][tc][s], acc[tr + 4][tc], 0, 0, 0);
  __builtin_amdgcn_s_setprio(0);
  SB();
  if constexpr (T < 7) {
    if constexpr (T < 6) { WAIT_VM8(); }  // B(T+1) done; A(T+2) stays in flight
    else                 { WAIT_VM0(); }  // T==6: drain B(7)
    SB(); BAR(); SB();
  }
}

extern "C" __global__ __launch_bounds__(256, 2) void attn_gemm(
    const float* __restrict__ A, const short* __restrict__ UT,
    const float* __restrict__ S, const float* __restrict__ vd,
    float* __restrict__ lout)
{
  __shared__ short As[2][8192];      // [buf][128 rows][64 k] bf16 swz, 16 KB ea

  const int tid = threadIdx.x;
  const int bx  = blockIdx.x;
  // XCD swizzle: 2048 blocks, 256/XCD; col-block pairs adjacent on one XCD.
  const int xcd = bx & 7;
  const int wg  = xcd * 256 + (bx >> 3);
  const int cb  = wg & 1;
  const int rb  = wg >> 1;           // 0..1023
  const int row0 = rb << 7;
  const int col0 = cb << 8;
  const int wave = tid >> 6;
  const int lane = tid & 63;
  const int wc = wave;               // 1 x 4 wave grid; each wave 128 x 64
  const int q = lane >> 4, l15 = lane & 15;

  GemmState st;
  st.As = As;

  // A staging: thread owns row tid>>1, k-half tid&1 (8 float4 / K-tile)
  const int arow = tid >> 1;
  const int ah   = tid & 1;
  st.aptr   = A + (size_t)(row0 + arow) * 512 + ah * 32;
  st.awbase = arow * 64 + ((((ah * 4) ^ (arow & 7)) & 7) << 3);

  // B fragment pointers: lane reads col (col0+wc*64+tc*16+l15), 16B at q*8
#pragma unroll
  for (int tc = 0; tc < 4; ++tc)
    st.bfp[tc] = UT + (size_t)(col0 + wc * 64 + tc * 16 + l15) * 512 + q * 8;

  // A fragment read base (swizzled; row&7 == l15&7)
  st.afrag0 = l15 * 64 + ((q ^ (l15 & 7)) << 3);

  floatx4 acc[8][4];
#pragma unroll
  for (int i = 0; i < 8; ++i)
#pragma unroll
    for (int j = 0; j < 4; ++j)
      acc[i][j] = (floatx4){0.f, 0.f, 0.f, 0.f};

  floatx4 areg[8];
  shortx8 bfr[2][4][2];

  // ------------------- prologue -------------------
  SB();
#pragma unroll
  for (int i = 0; i < 8; ++i) areg[i] = *(const floatx4*)(st.aptr + i * 4); // A(0)
  SB();
#pragma unroll
  for (int tc = 0; tc < 4; ++tc)
#pragma unroll
    for (int s = 0; s < 2; ++s)
      bfr[0][tc][s] = *(const shortx8*)(st.bfp[tc] + s * 32);               // B(0)
  SB();
  WAIT_VM8(); SB();                  // A(0) done; B(0) 8 in flight
#pragma unroll
  for (int gi = 0; gi < 4; ++gi) {
    uintx4 w;
    w.x = pack_bf_trunc(areg[2 * gi].x, areg[2 * gi].y);
    w.y = pack_bf_trunc(areg[2 * gi].z, areg[2 * gi].w);
    w.z = pack_bf_trunc(areg[2 * gi + 1].x, areg[2 * gi + 1].y);
    w.w = pack_bf_trunc(areg[2 * gi + 1].z, areg[2 * gi + 1].w);
    *(uintx4*)(&As[0][st.awbase ^ (gi * 8)]) = w;
  }
  SB();
#pragma unroll
  for (int i = 0; i < 8; ++i) areg[i] = *(const floatx4*)(st.aptr + 64 + i * 4); // A(1)
  SB();
  WAIT_VM8(); SB();                  // B(0) done; A(1) 8 in flight
  WAIT_LGKM0(); SB();
  BAR(); SB();

  // ------------------- main loop: 8 K-tiles of 64 -------------------
  kiter<0>(st, bfr, areg, acc);
  kiter<1>(st, bfr, areg, acc);
  kiter<2>(st, bfr, areg, acc);
  kiter<3>(st, bfr, areg, acc);
  kiter<4>(st, bfr, areg, acc);
  kiter<5>(st, bfr, areg, acc);
  kiter<6>(st, bfr, areg, acc);
  kiter<7>(st, bfr, areg, acc);

  // ------------- epilogue: e = tanh(acc + S[b][n]); dot with v; atomics -----
  const int bb = rb >> 4;            // 128 rows/block, 2048 rows/batch
  const float* Srow = S + bb * 512;
  float sv[4], vv[4];
#pragma unroll
  for (int tc = 0; tc < 4; ++tc) {
    int n = col0 + wc * 64 + tc * 16 + l15;
    sv[tc] = Srow[n];
    vv[tc] = vd[n];
  }
#pragma unroll
  for (int tr = 0; tr < 8; ++tr) {
#pragma unroll
    for (int r = 0; r < 4; ++r) {
      float ssum = 0.f;
#pragma unroll
      for (int tc = 0; tc < 4; ++tc) {
        float x = acc[tr][tc][r] + sv[tc];
        x = fminf(15.f, fmaxf(-15.f, x));
        float e2 = __expf(2.f * x);
        float e = (e2 - 1.f) / (e2 + 1.f);  // tanh
        ssum += e * vv[tc];
      }
      ssum += __shfl_xor(ssum, 1);
      ssum += __shfl_xor(ssum, 2);
      ssum += __shfl_xor(ssum, 4);
      ssum += __shfl_xor(ssum, 8);
      if (l15 == 0) {
        int row = row0 + tr * 16 + q * 4 + r;
        atomicAdd(lout + row, ssum);
      }
    }
  }
}

// ---------------------------------------------------------------------------
// Kernel 3: softmax over T=2048, in place on d_out. One block per batch.
// ---------------------------------------------------------------------------
extern "C" __global__ __launch_bounds__(256) void softmax_t(float* __restrict__ l)
{
  int b = blockIdx.x, tid = threadIdx.x;
  int wave = tid >> 6, lane = tid & 63;
  float* row = l + (size_t)b * 2048;
  float v[8];
  float mx = -3.4e38f;
#pragma unroll
  for (int i = 0; i < 8; ++i) { v[i] = row[tid + i * 256]; mx = fmaxf(mx, v[i]); }
#pragma unroll
  for (int m = 1; m < 64; m <<= 1) mx = fmaxf(mx, __shfl_xor(mx, m));
  __shared__ float red[8];
  if (lane == 0) red[wave] = mx;
  __syncthreads();
  mx = fmaxf(fmaxf(red[0], red[1]), fmaxf(red[2], red[3]));
  float s = 0.f;
#pragma unroll
  for (int i = 0; i < 8; ++i) { v[i] = __expf(v[i] - mx); s += v[i]; }
#pragma unroll
  for (int m = 1; m < 64; m <<= 1) s += __shfl_xor(s, m);
  if (lane == 0) red[4 + wave] = s;
  __syncthreads();
  s = red[4] + red[5] + red[6] + red[7];
  float inv = 1.f / s;
#pragma unroll
  for (int i = 0; i < 8; ++i) row[tid + i * 256] = v[i] * inv;
}

// ---------------------------------------------------------------------------
extern "C" void kernel_launch(void* const* d_in, const int* in_sizes, int n_in,
                              void* d_out, int out_size, void* d_ws, size_t ws_size,
                              hipStream_t stream) {
  const float* hidden = (const float*)d_in[0];
  const float* cell   = (const float*)d_in[1];
  const float* enc    = (const float*)d_in[2];
  const float* W_d    = (const float*)d_in[3];
  const float* b_wd   = (const float*)d_in[4];
  const float* U_d    = (const float*)d_in[5];
  const float* b_ud   = (const float*)d_in[6];
  const float* v_d    = (const float*)d_in[7];
  // d_in[8] = b_vd: constant shift over T -> softmax-invariant, unused.
  float* out = (float*)d_out;                     // logits then softmax, in place
  float* S   = (float*)d_ws;                      // 64*512 fp32   = 128 KB
  short* UT  = (short*)((char*)d_ws + 32768 * sizeof(float));  // 512*512 bf16

  hipLaunchKernelGGL(prep_kernel, dim3(512), dim3(256), 0, stream,
                     hidden, cell, W_d, b_wd, U_d, b_ud, S, UT, out);
  hipLaunchKernelGGL(attn_gemm, dim3(2048), dim3(256), 0, stream,
                     enc, UT, S, v_d, out);
  hipLaunchKernelGGL(softmax_t, dim3(64), dim3(256), 0, stream, out);
}

// Round 6
// 502.392 us; speedup vs baseline: 1.1433x; 1.1433x over previous
//
#include <hip/hip_runtime.h>
#include <cstdint>
#include <cstddef>

// Problem constants: B=64, T=2048, M=512, P=512

typedef float  floatx4 __attribute__((ext_vector_type(4)));
typedef short  shortx8 __attribute__((ext_vector_type(8)));
typedef unsigned int uintx4 __attribute__((ext_vector_type(4)));

__device__ __forceinline__ short f2bf_rne(float f) {
  unsigned u = __float_as_uint(f);
  unsigned r = u + 0x7FFFu + ((u >> 16) & 1u);
  return (short)(r >> 16);
}

// pack two fp32 -> two bf16 (truncation) in one v_perm_b32
__device__ __forceinline__ unsigned pack_bf_trunc(float lo, float hi) {
  return __builtin_amdgcn_perm(__float_as_uint(hi), __float_as_uint(lo), 0x07060302u);
}

#define SB() __builtin_amdgcn_sched_barrier(0)
#define WAIT_VM0() asm volatile("s_waitcnt vmcnt(0)" ::: "memory")
#define WAIT_VM4() asm volatile("s_waitcnt vmcnt(4)" ::: "memory")
#define WAIT_VM8() asm volatile("s_waitcnt vmcnt(8)" ::: "memory")
#define WAIT_LGKM0() asm volatile("s_waitcnt lgkmcnt(0)" ::: "memory")
#define BAR() __builtin_amdgcn_s_barrier()

// ---------------------------------------------------------------------------
// Kernel 1: prep.
//   blocks 0..127:   S[b][n] = ds@W_d + b_wd + b_ud  (fp32), 4-way ILP
//   blocks 128..383: UT[n][k] = bf16(U_d[k][n])  (plain row-major transpose)
//   blocks 384..511: zero d_out (logit accumulator)
// ---------------------------------------------------------------------------
extern "C" __global__ __launch_bounds__(256) void prep_kernel(
    const float* __restrict__ hidden, const float* __restrict__ cell,
    const float* __restrict__ W_d, const float* __restrict__ b_wd,
    const float* __restrict__ U_d, const float* __restrict__ b_ud,
    float* __restrict__ S, short* __restrict__ UT, float* __restrict__ lzero)
{
  int bx = blockIdx.x, tid = threadIdx.x;
  if (bx < 128) {
    int idx = bx * 256 + tid;          // 0..32767
    int b = idx >> 9, n = idx & 511;
    const float* h = hidden + b * 512;
    const float* c = cell   + b * 512;
    float a0 = b_wd[n] + b_ud[n], a1 = 0.f, a2 = 0.f, a3 = 0.f;
    for (int k = 0; k < 512; k += 4) {
      a0 = fmaf(h[k + 0], W_d[(k + 0) * 512 + n], a0);
      a1 = fmaf(h[k + 1], W_d[(k + 1) * 512 + n], a1);
      a2 = fmaf(h[k + 2], W_d[(k + 2) * 512 + n], a2);
      a3 = fmaf(h[k + 3], W_d[(k + 3) * 512 + n], a3);
    }
    for (int k = 0; k < 512; k += 4) {
      a0 = fmaf(c[k + 0], W_d[(k + 512) * 512 + n], a0);
      a1 = fmaf(c[k + 1], W_d[(k + 513) * 512 + n], a1);
      a2 = fmaf(c[k + 2], W_d[(k + 514) * 512 + n], a2);
      a3 = fmaf(c[k + 3], W_d[(k + 515) * 512 + n], a3);
    }
    S[idx] = (a0 + a1) + (a2 + a3);
  } else if (bx < 384) {
    int idx = (bx - 128) * 1024 + tid * 4;   // element index in UT (n*512+k)
    int n = idx >> 9, k0 = idx & 511;
    unsigned lo = (unsigned short)f2bf_rne(U_d[(size_t)(k0 + 0) * 512 + n]) |
                  ((unsigned)(unsigned short)f2bf_rne(U_d[(size_t)(k0 + 1) * 512 + n]) << 16);
    unsigned hi = (unsigned short)f2bf_rne(U_d[(size_t)(k0 + 2) * 512 + n]) |
                  ((unsigned)(unsigned short)f2bf_rne(U_d[(size_t)(k0 + 3) * 512 + n]) << 16);
    uint2 w; w.x = lo; w.y = hi;
    *(uint2*)(UT + idx) = w;
  } else {
    int idx = ((bx - 384) * 256 + tid) * 4;
    floatx4 z = {0.f, 0.f, 0.f, 0.f};
    *(floatx4*)(lzero + idx) = z;
  }
}

// ---------------------------------------------------------------------------
// Kernel 2: fused GEMM + tanh + dot(v) -> atomicAdd partial logits.
// 64x256 tile / block, 4 waves (1x4, each 64x64), BK=64, 1 barrier/K-tile.
// A: fp32 global -> regs (1-iter prefetch) -> bf16 pack -> swizzled LDS.
// B: L2-resident UT -> registers directly (no LDS), double-buffered frags.
// LDS: A only, 2 x 8 KB.  ~200 VGPR -> 2 waves/SIMD, 2 blocks/CU.
// Counted vmcnt, never 0 mid-loop.
// ---------------------------------------------------------------------------
struct GemmState {
  short (*As)[4096];                 // [2][64 rows][64 k] bf16 swizzled
  const float* aptr;
  const short* bfp[4];
  int afrag0, awbase;
};

template <int T>
__device__ __forceinline__ void kiter(
    GemmState& st, shortx8 (&bfr)[2][4][2], floatx4 (&areg)[4],
    floatx4 (&acc)[4][4])
{
  constexpr int CUR = T & 1;
  constexpr int NXT = CUR ^ 1;
  const short* Ab = &st.As[CUR][0];
  shortx8 af[4][2];

  // ---- 1: all af reads (cur);  2: issue B(T+1) frags ----
#pragma unroll
  for (int tr = 0; tr < 4; ++tr)
#pragma unroll
    for (int s = 0; s < 2; ++s)
      af[tr][s] = *(const shortx8*)(Ab + ((st.afrag0 + tr * 1024) ^ (s * 32)));
  SB();
  if constexpr (T < 7) {
#pragma unroll
    for (int tc = 0; tc < 4; ++tc)
#pragma unroll
      for (int s = 0; s < 2; ++s)
        bfr[NXT][tc][s] = *(const shortx8*)(st.bfp[tc] + (T + 1) * 64 + s * 32);
  }
  SB();
  // ---- 3: first MFMA cluster (tr 0..1) ----
  WAIT_LGKM0(); SB();
  __builtin_amdgcn_s_setprio(1);
#pragma unroll
  for (int tr = 0; tr < 2; ++tr)
#pragma unroll
    for (int tc = 0; tc < 4; ++tc)
#pragma unroll
      for (int s = 0; s < 2; ++s)
        acc[tr][tc] = __builtin_amdgcn_mfma_f32_16x16x32_bf16(
            af[tr][s], bfr[CUR][tc][s], acc[tr][tc], 0, 0, 0);
  __builtin_amdgcn_s_setprio(0);
  SB();
  // ---- 4: A(T+1) regs -> bf16 -> LDS[nxt] ----
  if constexpr (T < 7) {
    WAIT_VM8(); SB();                // A(T+1) done; B(T+1) 8 in flight
    short* An = &st.As[NXT][0];
    uintx4 w0, w1;
    w0.x = pack_bf_trunc(areg[0].x, areg[0].y);
    w0.y = pack_bf_trunc(areg[0].z, areg[0].w);
    w0.z = pack_bf_trunc(areg[1].x, areg[1].y);
    w0.w = pack_bf_trunc(areg[1].z, areg[1].w);
    w1.x = pack_bf_trunc(areg[2].x, areg[2].y);
    w1.y = pack_bf_trunc(areg[2].z, areg[2].w);
    w1.z = pack_bf_trunc(areg[3].x, areg[3].y);
    w1.w = pack_bf_trunc(areg[3].z, areg[3].w);
    *(uintx4*)(An + st.awbase)       = w0;
    *(uintx4*)(An + (st.awbase ^ 8)) = w1;
    SB();
  }
  // ---- 5: issue A(T+2) ----
  if constexpr (T < 6) {
#pragma unroll
    for (int i = 0; i < 4; ++i)
      areg[i] = *(const floatx4*)(st.aptr + (T + 2) * 64 + i * 4);
  }
  SB();
  // ---- 6: second MFMA cluster (tr 2..3) ----
  __builtin_amdgcn_s_setprio(1);
#pragma unroll
  for (int tr = 2; tr < 4; ++tr)
#pragma unroll
    for (int tc = 0; tc < 4; ++tc)
#pragma unroll
      for (int s = 0; s < 2; ++s)
        acc[tr][tc] = __builtin_amdgcn_mfma_f32_16x16x32_bf16(
            af[tr][s], bfr[CUR][tc][s], acc[tr][tc], 0, 0, 0);
  __builtin_amdgcn_s_setprio(0);
  SB();
  // ---- 7: counted drain + single barrier ----
  if constexpr (T < 7) {
    if constexpr (T < 6) { WAIT_VM4(); }  // B(T+1) done; A(T+2) in flight
    else                 { WAIT_VM0(); }  // T==6: drain B(7)
    SB();
    WAIT_LGKM0(); SB();              // my ds_writes to LDS[nxt] drained
    BAR(); SB();
  }
}

extern "C" __global__ __launch_bounds__(256, 2) void attn_gemm(
    const float* __restrict__ A, const short* __restrict__ UT,
    const float* __restrict__ S, const float* __restrict__ vd,
    float* __restrict__ lout)
{
  __shared__ short As[2][4096];      // [buf][64 rows][64 k] bf16 swz, 8 KB ea

  const int tid = threadIdx.x;
  const int bx  = blockIdx.x;
  // XCD swizzle: 4096 blocks, 512/XCD; col-block pairs adjacent on one XCD.
  const int xcd = bx & 7;
  const int wg  = xcd * 512 + (bx >> 3);
  const int cb  = wg & 1;
  const int rb  = wg >> 1;           // 0..2047
  const int row0 = rb << 6;
  const int col0 = cb << 8;
  const int lane = tid & 63;
  const int wc = tid >> 6;           // 1 x 4 wave grid; each wave 64 x 64
  const int q = lane >> 4, l15 = lane & 15;

  GemmState st;
  st.As = As;

  // A staging: thread owns row tid>>2, k-quarter tid&3 (4 float4 / K-tile)
  const int arow = tid >> 2;
  const int akq  = tid & 3;
  st.aptr   = A + (size_t)(row0 + arow) * 512 + akq * 16;
  st.awbase = arow * 64 + (((2 * akq) ^ (arow & 7)) << 3);

  // B fragment pointers: lane reads col (col0+wc*64+tc*16+l15), 16B at q*8
#pragma unroll
  for (int tc = 0; tc < 4; ++tc)
    st.bfp[tc] = UT + (size_t)(col0 + wc * 64 + tc * 16 + l15) * 512 + q * 8;

  // A fragment read base (swizzled; row&7 == l15&7)
  st.afrag0 = l15 * 64 + ((q ^ (l15 & 7)) << 3);

  floatx4 acc[4][4];
#pragma unroll
  for (int i = 0; i < 4; ++i)
#pragma unroll
    for (int j = 0; j < 4; ++j)
      acc[i][j] = (floatx4){0.f, 0.f, 0.f, 0.f};

  floatx4 areg[4];
  shortx8 bfr[2][4][2];

  // ------------------- prologue -------------------
  SB();
#pragma unroll
  for (int i = 0; i < 4; ++i) areg[i] = *(const floatx4*)(st.aptr + i * 4); // A(0)
  SB();
#pragma unroll
  for (int tc = 0; tc < 4; ++tc)
#pragma unroll
    for (int s = 0; s < 2; ++s)
      bfr[0][tc][s] = *(const shortx8*)(st.bfp[tc] + s * 32);               // B(0)
  SB();
  WAIT_VM8(); SB();                  // A(0) done; B(0) 8 in flight
  {
    uintx4 w0, w1;
    w0.x = pack_bf_trunc(areg[0].x, areg[0].y);
    w0.y = pack_bf_trunc(areg[0].z, areg[0].w);
    w0.z = pack_bf_trunc(areg[1].x, areg[1].y);
    w0.w = pack_bf_trunc(areg[1].z, areg[1].w);
    w1.x = pack_bf_trunc(areg[2].x, areg[2].y);
    w1.y = pack_bf_trunc(areg[2].z, areg[2].w);
    w1.z = pack_bf_trunc(areg[3].x, areg[3].y);
    w1.w = pack_bf_trunc(areg[3].z, areg[3].w);
    *(uintx4*)(&As[0][st.awbase])       = w0;
    *(uintx4*)(&As[0][st.awbase ^ 8])   = w1;
  }
  SB();
#pragma unroll
  for (int i = 0; i < 4; ++i) areg[i] = *(const floatx4*)(st.aptr + 64 + i * 4); // A(1)
  SB();
  WAIT_VM4(); SB();                  // B(0) done; A(1) 4 in flight
  WAIT_LGKM0(); SB();
  BAR(); SB();

  // ------------------- main loop: 8 K-tiles of 64 -------------------
  kiter<0>(st, bfr, areg, acc);
  kiter<1>(st, bfr, areg, acc);
  kiter<2>(st, bfr, areg, acc);
  kiter<3>(st, bfr, areg, acc);
  kiter<4>(st, bfr, areg, acc);
  kiter<5>(st, bfr, areg, acc);
  kiter<6>(st, bfr, areg, acc);
  kiter<7>(st, bfr, areg, acc);

  // ------------- epilogue: e = tanh(acc + S[b][n]); dot with v; atomics -----
  const int bb = rb >> 5;            // 64 rows/block, 2048 rows/batch
  const float* Srow = S + bb * 512;
  float sv[4], vv[4];
#pragma unroll
  for (int tc = 0; tc < 4; ++tc) {
    int n = col0 + wc * 64 + tc * 16 + l15;
    sv[tc] = Srow[n];
    vv[tc] = vd[n];
  }
#pragma unroll
  for (int tr = 0; tr < 4; ++tr) {
#pragma unroll
    for (int r = 0; r < 4; ++r) {
      float ssum = 0.f;
#pragma unroll
      for (int tc = 0; tc < 4; ++tc) {
        float x = acc[tr][tc][r] + sv[tc];
        x = fminf(15.f, fmaxf(-15.f, x));
        float e2 = __expf(2.f * x);
        float e = (e2 - 1.f) / (e2 + 1.f);  // tanh
        ssum += e * vv[tc];
      }
      ssum += __shfl_xor(ssum, 1);
      ssum += __shfl_xor(ssum, 2);
      ssum += __shfl_xor(ssum, 4);
      ssum += __shfl_xor(ssum, 8);
      if (l15 == 0) {
        int row = row0 + tr * 16 + q * 4 + r;
        atomicAdd(lout + row, ssum);
      }
    }
  }
}

// ---------------------------------------------------------------------------
// Kernel 3: softmax over T=2048, in place on d_out. One block per batch.
// ---------------------------------------------------------------------------
extern "C" __global__ __launch_bounds__(256) void softmax_t(float* __restrict__ l)
{
  int b = blockIdx.x, tid = threadIdx.x;
  int wave = tid >> 6, lane = tid & 63;
  float* row = l + (size_t)b * 2048;
  float v[8];
  float mx = -3.4e38f;
#pragma unroll
  for (int i = 0; i < 8; ++i) { v[i] = row[tid + i * 256]; mx = fmaxf(mx, v[i]); }
#pragma unroll
  for (int m = 1; m < 64; m <<= 1) mx = fmaxf(mx, __shfl_xor(mx, m));
  __shared__ float red[8];
  if (lane == 0) red[wave] = mx;
  __syncthreads();
  mx = fmaxf(fmaxf(red[0], red[1]), fmaxf(red[2], red[3]));
  float s = 0.f;
#pragma unroll
  for (int i = 0; i < 8; ++i) { v[i] = __expf(v[i] - mx); s += v[i]; }
#pragma unroll
  for (int m = 1; m < 64; m <<= 1) s += __shfl_xor(s, m);
  if (lane == 0) red[4 + wave] = s;
  __syncthreads();
  s = red[4] + red[5] + red[6] + red[7];
  float inv = 1.f / s;
#pragma unroll
  for (int i = 0; i < 8; ++i) row[tid + i * 256] = v[i] * inv;
}

// ---------------------------------------------------------------------------
extern "C" void kernel_launch(void* const* d_in, const int* in_sizes, int n_in,
                              void* d_out, int out_size, void* d_ws, size_t ws_size,
                              hipStream_t stream) {
  const float* hidden = (const float*)d_in[0];
  const float* cell   = (const float*)d_in[1];
  const float* enc    = (const float*)d_in[2];
  const float* W_d    = (const float*)d_in[3];
  const float* b_wd   = (const float*)d_in[4];
  const float* U_d    = (const float*)d_in[5];
  const float* b_ud   = (const float*)d_in[6];
  const float* v_d    = (const float*)d_in[7];
  // d_in[8] = b_vd: constant shift over T -> softmax-invariant, unused.
  float* out = (float*)d_out;                     // logits then softmax, in place
  float* S   = (float*)d_ws;                      // 64*512 fp32   = 128 KB
  short* UT  = (short*)((char*)d_ws + 32768 * sizeof(float));  // 512*512 bf16

  hipLaunchKernelGGL(prep_kernel, dim3(512), dim3(256), 0, stream,
                     hidden, cell, W_d, b_wd, U_d, b_ud, S, UT, out);
  hipLaunchKernelGGL(attn_gemm, dim3(4096), dim3(256), 0, stream,
                     enc, UT, S, v_d, out);
  hipLaunchKernelGGL(softmax_t, dim3(64), dim3(256), 0, stream, out);
}